// Round 3
// baseline (1153.990 us; speedup 1.0000x reference)
//
#include <hip/hip_runtime.h>

static constexpr int D        = 64;   // N_FACTORS
static constexpr int N_LAYERS = 3;
static constexpr int SH       = 7;    // 128 rows per bucket
static constexpr int RPB      = 1 << SH;
static constexpr int CAP      = 8192; // max edges per bucket (mean 4096, sigma 64)

// ===========================================================================
// k_init: emb0 = concat(user_emb, item_emb) -> cur and acc
// ===========================================================================
__global__ void k_init(const float4* __restrict__ ue, const float4* __restrict__ ie,
                       float4* __restrict__ cur, float4* __restrict__ acc,
                       int nUser4, int nTot4) {
    int stride = gridDim.x * blockDim.x;
    for (int i = blockIdx.x * blockDim.x + threadIdx.x; i < nTot4; i += stride) {
        float4 v = (i < nUser4) ? ue[i] : ie[i - nUser4];
        cur[i] = v;
        acc[i] = v;
    }
}

// ===========================================================================
// CSR build, two-level:
//   bucket = row >> SH (1172 buckets), 8 XCD sub-groups per bucket.
//   cnt/cur layout is grp-major [g*NB + b] so each XCD group's counters live
//   on disjoint cache lines (no cross-XCD atomic/sector bouncing).
//   Final ecv layout is bucket-major: region of bucket b = [S[8b], S[8b+8]).
// ===========================================================================
__global__ void k_bhist(const int* __restrict__ row, int* __restrict__ cnt,
                        int nnz, int NB) {
    int g = blockIdx.x & 7;
    int stride = gridDim.x * blockDim.x;
    for (int e = blockIdx.x * blockDim.x + threadIdx.x; e < nnz; e += stride)
        atomicAdd(&cnt[g * NB + (row[e] >> SH)], 1);
}

// Single-block exclusive scan over M = NB*8 counts in (bucket-major, grp-minor)
// order; writes S[0..M] (with sentinel) and initializes cur (grp-major).
__global__ void k_scan(const int* __restrict__ cnt, int* __restrict__ S,
                       int* __restrict__ cur, int NB, int M) {
    __shared__ int tsum[256];
    int tid = threadIdx.x;
    int per = (M + 255) / 256;
    int i0  = tid * per;
    int sum = 0;
    for (int k = 0; k < per; ++k) {
        int i = i0 + k;
        if (i < M) sum += cnt[(i & 7) * NB + (i >> 3)];
    }
    tsum[tid] = sum;
    __syncthreads();
    for (int off = 1; off < 256; off <<= 1) {
        int v = (tid >= off) ? tsum[tid - off] : 0;
        __syncthreads();
        tsum[tid] += v;
        __syncthreads();
    }
    int run = tsum[tid] - sum;   // exclusive prefix of this thread's chunk
    for (int k = 0; k < per; ++k) {
        int i = i0 + k;
        if (i < M) {
            int b = i >> 3, g = i & 7;
            int c = cnt[g * NB + b];
            S[i] = run;
            cur[g * NB + b] = run;
            run += c;
        }
    }
    if (tid == 255) S[M] = tsum[255];   // total = nnz
}

// Partition scatter: ecv[p] = (packed(row_low, col), val). Write frontier per
// XCD group is 1172 x 64B = 75 KB, L2-resident -> full-sector writebacks.
__global__ void k_pscatter(const int* __restrict__ row, const int* __restrict__ col,
                           const float* __restrict__ val, int* __restrict__ cur,
                           int2* __restrict__ ecv, int nnz, int NB) {
    int g = blockIdx.x & 7;
    int stride = gridDim.x * blockDim.x;
    for (int e = blockIdx.x * blockDim.x + threadIdx.x; e < nnz; e += stride) {
        int r = row[e];
        int p = atomicAdd(&cur[g * NB + (r >> SH)], 1);
        ecv[p] = make_int2(((r & (RPB - 1)) << 18) | col[e], __float_as_int(val[e]));
    }
}

// Per-bucket LDS counting sort (in place) + rowptr emission.
__global__ __launch_bounds__(256) void k_bsort(const int* __restrict__ S,
                                               int2* __restrict__ ecv,
                                               int* __restrict__ rowptr,
                                               int NB, int N) {
    __shared__ int2 ebuf[CAP];
    __shared__ int hist[RPB];
    __shared__ int sc[RPB];
    __shared__ int cur[RPB];
    int b    = blockIdx.x;
    int tid  = threadIdx.x;
    int base = S[b * 8];
    int cnt  = S[(b + 1) * 8] - base;
    if (cnt > CAP) cnt = CAP;            // unreachable for this data; guards LDS
    if (tid < RPB) hist[tid] = 0;
    __syncthreads();
    for (int i = tid; i < cnt; i += 256) {
        int2 e = ecv[base + i];
        ebuf[i] = e;
        atomicAdd(&hist[(unsigned)e.x >> 18], 1);
    }
    __syncthreads();
    int h = (tid < RPB) ? hist[tid] : 0;
    if (tid < RPB) sc[tid] = h;
    __syncthreads();
    for (int off = 1; off < RPB; off <<= 1) {
        int v = (tid >= off && tid < RPB) ? sc[tid - off] : 0;
        __syncthreads();
        if (tid < RPB) sc[tid] += v;
        __syncthreads();
    }
    if (tid < RPB) {
        int excl = sc[tid] - h;
        cur[tid] = excl;
        int gr = b * RPB + tid;
        if (gr <= N) rowptr[gr] = base + excl;
    }
    __syncthreads();
    for (int i = tid; i < cnt; i += 256) {
        int2 e = ebuf[i];
        int r  = (unsigned)e.x >> 18;
        int p  = atomicAdd(&cur[r], 1);
        ecv[base + p] = make_int2(e.x & 0x3FFFF, e.y);
    }
}

// ===========================================================================
// SpMM: one wave per row. lane = grp*16 + ch; grp in [0,4) picks one of 4
// edges per step, ch picks the 16B chunk of the 256B x-row. Unroll 2 ->
// up to 2 float4 gathers in flight per lane. Cross-group shfl_xor reduce.
// ===========================================================================
template <bool WRITE_Y, bool LAST>
__global__ void k_spmm(const int* __restrict__ rowptr, const int2* __restrict__ ecv,
                       const float* __restrict__ x, float* __restrict__ y,
                       float* __restrict__ acc, int N) {
    int wid = (blockIdx.x * blockDim.x + threadIdx.x) >> 6;
    if (wid >= N) return;
    int lane = threadIdx.x & 63;
    int grp  = lane >> 4;
    int ch   = lane & 15;
    int e0 = rowptr[wid];
    int e1 = rowptr[wid + 1];
    float4 s = make_float4(0.f, 0.f, 0.f, 0.f);
    for (int e = e0 + grp; e < e1; e += 8) {
        int2 a = ecv[e];
        bool v2 = (e + 4) < e1;
        int2 c = v2 ? ecv[e + 4] : make_int2(0, 0);
        const float4 xa = *(const float4*)(x + ((size_t)a.x << 6) + ch * 4);
        const float4 xc = *(const float4*)(x + ((size_t)c.x << 6) + ch * 4);
        float va = __int_as_float(a.y);
        float vc = v2 ? __int_as_float(c.y) : 0.f;
        s.x += va * xa.x + vc * xc.x;
        s.y += va * xa.y + vc * xc.y;
        s.z += va * xa.z + vc * xc.z;
        s.w += va * xa.w + vc * xc.w;
    }
    // reduce the 4 edge-groups (xor 16, 32 preserve ch = lane&15)
    s.x += __shfl_xor(s.x, 16); s.y += __shfl_xor(s.y, 16);
    s.z += __shfl_xor(s.z, 16); s.w += __shfl_xor(s.w, 16);
    s.x += __shfl_xor(s.x, 32); s.y += __shfl_xor(s.y, 32);
    s.z += __shfl_xor(s.z, 32); s.w += __shfl_xor(s.w, 32);
    if (grp == 0) {
        size_t o = (size_t)wid * D + ch * 4;
        if (WRITE_Y) *(float4*)(y + o) = s;
        float4 av = *(const float4*)(acc + o);
        av.x += s.x; av.y += s.y; av.z += s.z; av.w += s.w;
        if (LAST) {
            av.x *= 0.25f; av.y *= 0.25f; av.z *= 0.25f; av.w *= 0.25f;
        }
        *(float4*)(acc + o) = av;
    }
}

// ===========================================================================
// Fallback (round-1 atomic path) if ws is too small
// ===========================================================================
__global__ void k_spmm_atomic(const int* __restrict__ row, const int* __restrict__ col,
                              const float* __restrict__ val, const float* __restrict__ x,
                              float* __restrict__ y, int nnz) {
    long long total  = (long long)nnz * 16;
    long long stride = (long long)gridDim.x * blockDim.x;
    for (long long idx = (long long)blockIdx.x * blockDim.x + threadIdx.x;
         idx < total; idx += stride) {
        int e = (int)(idx >> 4);
        int c = (int)(idx & 15);
        int r = row[e];
        int ssrc = col[e];
        float v = val[e];
        float4 xv = *(const float4*)(x + (size_t)ssrc * D + c * 4);
        float* yp = y + (size_t)r * D + c * 4;
        atomicAdd(yp + 0, v * xv.x);
        atomicAdd(yp + 1, v * xv.y);
        atomicAdd(yp + 2, v * xv.z);
        atomicAdd(yp + 3, v * xv.w);
    }
}

__global__ void k_acc(const float4* __restrict__ nxt, float4* __restrict__ acc,
                      float scale, int n4) {
    int stride = gridDim.x * blockDim.x;
    for (int i = blockIdx.x * blockDim.x + threadIdx.x; i < n4; i += stride) {
        float4 a = acc[i];
        float4 b = nxt[i];
        a.x = (a.x + b.x) * scale;
        a.y = (a.y + b.y) * scale;
        a.z = (a.z + b.z) * scale;
        a.w = (a.w + b.w) * scale;
        acc[i] = a;
    }
}

// ===========================================================================
extern "C" void kernel_launch(void* const* d_in, const int* in_sizes, int n_in,
                              void* d_out, int out_size, void* d_ws, size_t ws_size,
                              hipStream_t stream) {
    const float* ue  = (const float*)d_in[0];
    const float* ie  = (const float*)d_in[1];
    const int*   row = (const int*)  d_in[2];
    const int*   col = (const int*)  d_in[3];
    const float* val = (const float*)d_in[4];

    const int n_users = in_sizes[0] / D;
    const int n_items = in_sizes[1] / D;
    const int nnz     = in_sizes[2];
    const int N       = n_users + n_items;
    const int NB      = (N + RPB - 1) >> SH;   // 1172
    const int M       = NB * 8;

    float* acc = (float*)d_out;
    const size_t denseB = (size_t)N * D * sizeof(float);
    auto aup = [](size_t x) { return (x + 255) & ~(size_t)255; };

    size_t off = 0;
    float* bufA   = (float*)((char*)d_ws + off); off += aup(denseB);
    float* bufB   = (float*)((char*)d_ws + off); off += aup(denseB);
    int2*  ecv    = (int2*) ((char*)d_ws + off); off += aup((size_t)nnz * 8);
    int*   rowptr = (int*)  ((char*)d_ws + off); off += aup((size_t)(N + 1) * 4);
    int*   cnt    = (int*)  ((char*)d_ws + off); off += aup((size_t)M * 4);
    int*   cur    = (int*)  ((char*)d_ws + off); off += aup((size_t)M * 4);
    int*   S      = (int*)  ((char*)d_ws + off); off += aup((size_t)(M + 1) * 4);
    const size_t needCSR = off;

    const int nTot4  = N * D / 4;
    const int nUser4 = n_users * D / 4;

    if (ws_size >= needCSR) {
        // ---- CSR build ----
        hipMemsetAsync(cnt, 0, (size_t)M * 4, stream);
        k_bhist<<<1024, 256, 0, stream>>>(row, cnt, nnz, NB);
        k_scan<<<1, 256, 0, stream>>>(cnt, S, cur, NB, M);
        k_pscatter<<<1024, 256, 0, stream>>>(row, col, val, cur, ecv, nnz, NB);
        k_bsort<<<NB, 256, 0, stream>>>(S, ecv, rowptr, NB, N);

        // ---- init + 3 fused SpMM layers ----
        k_init<<<2048, 256, 0, stream>>>((const float4*)ue, (const float4*)ie,
                                         (float4*)bufA, (float4*)acc, nUser4, nTot4);
        int grid = (N + 3) / 4;   // one wave per row, 4 rows per 256-thr block
        k_spmm<true,  false><<<grid, 256, 0, stream>>>(rowptr, ecv, bufA, bufB, acc, N);
        k_spmm<true,  false><<<grid, 256, 0, stream>>>(rowptr, ecv, bufB, bufA, acc, N);
        k_spmm<false, true ><<<grid, 256, 0, stream>>>(rowptr, ecv, bufA, bufA, acc, N);
    } else {
        // ---- fallback: atomic scatter path ----
        float* fa = (float*)d_ws;
        float* fb = fa + (size_t)N * D;
        k_init<<<2048, 256, 0, stream>>>((const float4*)ue, (const float4*)ie,
                                         (float4*)fa, (float4*)acc, nUser4, nTot4);
        float* curp = fa;
        float* nxt  = fb;
        for (int l = 0; l < N_LAYERS; ++l) {
            hipMemsetAsync(nxt, 0, denseB, stream);
            k_spmm_atomic<<<8192, 256, 0, stream>>>(row, col, val, curp, nxt, nnz);
            float scale = (l == N_LAYERS - 1) ? (1.0f / (N_LAYERS + 1)) : 1.0f;
            k_acc<<<2048, 256, 0, stream>>>((const float4*)nxt, (float4*)acc, scale, nTot4);
            float* t = curp; curp = nxt; nxt = t;
        }
    }
}